// Round 1
// 182.522 us; speedup vs baseline: 1.0107x; 1.0107x over previous
//
#include <hip/hip_runtime.h>
#include <hip/hip_bf16.h>

// DynamicPatching: B=32, C=64, T=8192, S=64 segments per batch.
// out[b,s,c,p] = (p < end[b,s]-start[b,s]) ? tensor[b,c,start[b,s]+p] : 0
// Output shape (B, S, C, max_length) float32. Measured max_length == 256.
//
// R1: 131k tiny blocks -> 98 us (wg-dispatch-rate bound).
// R2: block/(b,s), scalar clamped loads, PLAIN float4 stores -> ~60 us.
// R4/R5/R6: better load structures + NT stores -> 60/57/54 us.
// R7: plain stores (nt bypass writes at ~half rate on gfx950).
// R8 (this): MLP theory — each wave had exactly 1 outstanding load + 1 store
//     (latency-bound at ~3.1 TB/s, not BW-bound; fill/copy reach 6.7 TB/s).
//     Now one wave handles 4 c-rows of the SAME (b,s): descriptor + shuffle
//     control (a, jmax) are identical, so 4 independent loads issue
//     back-to-back and the 4 stores form one contiguous 4 KB block.
//     Predict kernel ~54 -> ~35 us, kernel BW ~3.1 -> ~5.5+ TB/s.

#define DP_B 32
#define DP_C 64
#define DP_T 8192
#define DP_S 64
#define DP_ILP 4   // c-rows per wave

typedef float vfloat4 __attribute__((ext_vector_type(4)));

// Fast path: L == 256 (one wave == 4 (b,s,c) rows of 64 float4 quads each).
__global__ __launch_bounds__(256) void dp_kernel_flat4(
    const float* __restrict__ tensor,      // (B, C, T)
    const int* __restrict__ change_points, // (B, S+1)
    float* __restrict__ out) {             // (B, S, C, 256)
  const int lane = threadIdx.x & 63;
  const int wave = (blockIdx.x * 256 + threadIdx.x) >> 6;  // 0..32767
  const int cg   = wave & (16 / (DP_ILP / 4) - 1);  // 16 groups of 4 c's
  const int bs   = wave >> 4;
  const int b    = bs >> 6;
  const int s    = bs & 63;
  const int c0   = cg * DP_ILP;

  // Wave-uniform segment descriptor; force scalar load via readfirstlane.
  const int didx  = __builtin_amdgcn_readfirstlane(b * (DP_S + 1) + s);
  const int start = change_points[didx];
  const int end   = change_points[didx + 1];
  const int len   = end - start;
  const int a      = start & 3;   // word misalignment within a quad
  const int base_q = start >> 2;  // first aligned quad
  const int jmax   = ((end - 1) >> 2) - base_q;  // last valid aligned quad

  const float* __restrict__ arow0 =
      tensor + ((size_t)b * DP_C + c0) * DP_T + (size_t)base_q * 4;

  // 4 independent row loads (identical exec mask / addresses differ by 32 KB).
  vfloat4 q[DP_ILP] = {{0, 0, 0, 0}, {0, 0, 0, 0}, {0, 0, 0, 0}, {0, 0, 0, 0}};
  if (lane <= jmax) {
#pragma unroll
    for (int i = 0; i < DP_ILP; ++i)
      q[i] = *(const vfloat4*)(arow0 + (size_t)i * DP_T + (size_t)lane * 4);
  }

  vfloat4 val[DP_ILP];
  if (a == 0) {  // aligned segment: no cross-lane traffic (~25% of rows)
#pragma unroll
    for (int i = 0; i < DP_ILP; ++i) val[i] = q[i];
  } else {
    vfloat4 nxt[DP_ILP];
#pragma unroll
    for (int i = 0; i < DP_ILP; ++i) {
      nxt[i].x = __shfl_down(q[i].x, 1);
      nxt[i].y = __shfl_down(q[i].y, 1);
      nxt[i].z = __shfl_down(q[i].z, 1);
      nxt[i].w = __shfl_down(q[i].w, 1);
    }
    if (lane == 63 && jmax >= 64) {  // window spans 65 aligned quads
#pragma unroll
      for (int i = 0; i < DP_ILP; ++i)
        nxt[i] = *(const vfloat4*)(arow0 + (size_t)i * DP_T + 64 * 4);
    }
    switch (a) {  // wave-uniform
      case 1:
#pragma unroll
        for (int i = 0; i < DP_ILP; ++i) {
          val[i].x = q[i].y; val[i].y = q[i].z;
          val[i].z = q[i].w; val[i].w = nxt[i].x;
        }
        break;
      case 2:
#pragma unroll
        for (int i = 0; i < DP_ILP; ++i) {
          val[i].x = q[i].z; val[i].y = q[i].w;
          val[i].z = nxt[i].x; val[i].w = nxt[i].y;
        }
        break;
      default:
#pragma unroll
        for (int i = 0; i < DP_ILP; ++i) {
          val[i].x = q[i].w; val[i].y = nxt[i].x;
          val[i].z = nxt[i].y; val[i].w = nxt[i].z;
        }
        break;
    }
  }

  const int p = lane * 4;  // output word base within each row (same all rows)
  const bool m0 = (p + 0 < len), m1 = (p + 1 < len);
  const bool m2 = (p + 2 < len), m3 = (p + 3 < len);

  // 4 stores = one contiguous 4 KB block per wave (c stride in out = 1 KB).
  float* __restrict__ drow =
      out + ((size_t)bs * DP_C + c0) * 256 + (size_t)lane * 4;
#pragma unroll
  for (int i = 0; i < DP_ILP; ++i) {
    vfloat4 v = val[i];
    v.x = m0 ? v.x : 0.0f;
    v.y = m1 ? v.y : 0.0f;
    v.z = m2 ? v.z : 0.0f;
    v.w = m3 ? v.w : 0.0f;
    *(vfloat4*)(drow + (size_t)i * 256) = v;
  }
}

// Generic fallback (any max_len): scalar, one block per (b,s,c) row.
__global__ __launch_bounds__(256) void dp_kernel_generic(
    const float* __restrict__ tensor,
    const int* __restrict__ change_points,
    float* __restrict__ out, int max_len) {
  const int c = blockIdx.x;
  const int bs = blockIdx.y;
  const int b = bs >> 6;
  const int s = bs & 63;
  const int start = change_points[b * (DP_S + 1) + s];
  const int len = change_points[b * (DP_S + 1) + s + 1] - start;
  const float* __restrict__ src = tensor + ((size_t)b * DP_C + c) * DP_T;
  float* __restrict__ dst = out + ((size_t)bs * DP_C + c) * (size_t)max_len;
  for (int p = threadIdx.x; p < max_len; p += blockDim.x) {
    float t = 0.0f;
    if (p < len) t = src[start + p];
    dst[p] = t;
  }
}

extern "C" void kernel_launch(void* const* d_in, const int* in_sizes, int n_in,
                              void* d_out, int out_size, void* d_ws, size_t ws_size,
                              hipStream_t stream) {
  const float* tensor = (const float*)d_in[0];
  const int* change_points = (const int*)d_in[1];
  const int max_len = out_size / (DP_B * DP_S * DP_C);
  float* out = (float*)d_out;

  if (max_len == 256) {
    // waves = B*S*C / DP_ILP = 32768; threads = 32768*64; blocks @256 thr.
    const int nwaves = DP_B * DP_S * DP_C / DP_ILP;
    dp_kernel_flat4<<<dim3(nwaves * 64 / 256), dim3(256), 0, stream>>>(
        tensor, change_points, out);
  } else {
    dp_kernel_generic<<<dim3(DP_C, DP_B * DP_S), dim3(256), 0, stream>>>(
        tensor, change_points, out, max_len);
  }
}